// Round 2
// baseline (196.869 us; speedup 1.0000x reference)
//
#include <hip/hip_runtime.h>
#include <hip/hip_bf16.h>

#define LSEQ 256
#define CIN  8
#define COUT 8
#define HU   32

// ---------------------------------------------------------------------------
// Kernel 1: generate the Toeplitz continuous kernel K[o][c][d], d = i-j in
// [0, L).  dt = t[j]-t[i] = -(d)/L exactly (t = arange(L)/L).
// One thread per (o,c,d): 16384 threads = 64 blocks x 256.
// ---------------------------------------------------------------------------
__global__ __launch_bounds__(256) void ck_gen(
    const float* __restrict__ v1, const float* __restrict__ g1,
    const float* __restrict__ b1, const float* __restrict__ v2,
    const float* __restrict__ g2, const float* __restrict__ b2,
    const float* __restrict__ w3, const float* __restrict__ b3,
    float* __restrict__ K)
{
    __shared__ float a1[HU], wc1[HU], wo1[HU], b1s[HU], b2s[HU], w3s[HU];
    __shared__ float w2n[HU][HU];
    __shared__ float b3s;

    const int tid = threadIdx.x;
    if (tid < HU) {
        // weight_norm row of v1 (3 columns)
        float vx = v1[tid * 3 + 0];
        float vy = v1[tid * 3 + 1];
        float vz = v1[tid * 3 + 2];
        float inv = g1[tid] * rsqrtf(vx * vx + vy * vy + vz * vz);
        a1[tid]  = vx * inv;   // multiplies dt
        wc1[tid] = vy * inv;   // multiplies c
        wo1[tid] = vz * inv;   // multiplies o
        b1s[tid] = b1[tid];
        b2s[tid] = b2[tid];
        w3s[tid] = w3[tid];
        // weight_norm row tid of v2 (32 columns)
        float s = 0.f;
        #pragma unroll
        for (int h = 0; h < HU; ++h) {
            float v = v2[tid * HU + h];
            s += v * v;
        }
        float inv2 = g2[tid] * rsqrtf(s);
        #pragma unroll
        for (int h = 0; h < HU; ++h)
            w2n[tid][h] = v2[tid * HU + h] * inv2;
    }
    if (tid == 0) b3s = b3[0];
    __syncthreads();

    const int n  = blockIdx.x * 256 + tid;   // n = (o*8 + c)*256 + d
    const int d  = n & (LSEQ - 1);
    const int oc = n >> 8;                   // 0..63
    const float cf = (float)(oc & 7);
    const float of = (float)(oc >> 3);
    const float dt = -(float)d * (1.0f / (float)LSEQ);

    // layer 1: h1[h] = sin(dt*W1[h,0] + c*W1[h,1] + o*W1[h,2] + b1[h])
    float h1[HU];
    #pragma unroll
    for (int h = 0; h < HU; ++h) {
        float z = fmaf(dt, a1[h], fmaf(cf, wc1[h], fmaf(of, wo1[h], b1s[h])));
        h1[h] = sinf(z);
    }

    // layer 2 + output dot: K = sum_k sin(dot(h1, W2n[k]) + b2[k]) * w3[k] + b3
    float acc = b3s;
    #pragma unroll
    for (int k = 0; k < HU; ++k) {
        float z = b2s[k];
        #pragma unroll
        for (int h = 0; h < HU; ++h)
            z = fmaf(h1[h], w2n[k][h], z);
        acc = fmaf(sinf(z), w3s[k], acc);
    }
    K[n] = acc;
}

// ---------------------------------------------------------------------------
// Kernel 2: causal conv  out[i,o] = sum_c sum_{j<=i} K[o,c,i-j] * x[j,c]
// One thread per (i,o): 2048 threads = 8 blocks x 256.  x staged in LDS,
// K (64 KiB) is L1/L2 resident.
// ---------------------------------------------------------------------------
__global__ __launch_bounds__(256) void ck_conv(
    const float* __restrict__ x, const float* __restrict__ K,
    float* __restrict__ out)
{
    __shared__ float xs[LSEQ][CIN];
    const int tid = threadIdx.x;
    #pragma unroll
    for (int idx = tid; idx < LSEQ * CIN; idx += 256)
        ((float*)xs)[idx] = x[idx];
    __syncthreads();

    const int n = blockIdx.x * 256 + tid;
    const int o = n & 7;
    const int i = n >> 3;

    float acc = 0.f;
    for (int c = 0; c < CIN; ++c) {
        const float* Kr = K + ((o * CIN + c) << 8);
        float a = 0.f;
        for (int j = 0; j <= i; ++j)
            a = fmaf(Kr[i - j], xs[j][c], a);
        acc += a;
    }
    out[i * COUT + o] = acc;
}

extern "C" void kernel_launch(void* const* d_in, const int* in_sizes, int n_in,
                              void* d_out, int out_size, void* d_ws, size_t ws_size,
                              hipStream_t stream) {
    const float* x  = (const float*)d_in[0];
    // d_in[1] = t (unused: t = arange(L)/L so dt = -(i-j)/L in closed form)
    const float* v1 = (const float*)d_in[2];
    const float* g1 = (const float*)d_in[3];
    const float* b1 = (const float*)d_in[4];
    const float* v2 = (const float*)d_in[5];
    const float* g2 = (const float*)d_in[6];
    const float* b2 = (const float*)d_in[7];
    const float* w3 = (const float*)d_in[8];
    const float* b3 = (const float*)d_in[9];
    float* out = (float*)d_out;
    float* K   = (float*)d_ws;  // COUT*CIN*LSEQ floats = 64 KiB

    ck_gen<<<dim3((COUT * CIN * LSEQ) / 256), dim3(256), 0, stream>>>(
        v1, g1, b1, v2, g2, b2, w3, b3, K);
    ck_conv<<<dim3((LSEQ * COUT) / 256), dim3(256), 0, stream>>>(x, K, out);
}

// Round 3
// 86.040 us; speedup vs baseline: 2.2881x; 2.2881x over previous
//
#include <hip/hip_runtime.h>
#include <hip/hip_bf16.h>

#define LSEQ 256
#define CIN  8
#define COUT 8
#define HU   32

// ---------------------------------------------------------------------------
// Kernel 1: Toeplitz kernel-gen  K[o][c][d], d = i-j in [0,L).
// dt = t[j]-t[i] = -d/L exactly (t = arange(L)/L).
// Grid: 256 blocks x 256 threads. Block handles 64 points (o,c,d);
// wave w (= k-quarter) computes 8 of the 32 layer-2 units for all 64 points.
// w2n row reads are wave-uniform -> conflict-free LDS broadcast.
// ---------------------------------------------------------------------------
__global__ __launch_bounds__(256) void ck_gen(
    const float* __restrict__ v1, const float* __restrict__ g1,
    const float* __restrict__ b1, const float* __restrict__ v2,
    const float* __restrict__ g2, const float* __restrict__ b2,
    const float* __restrict__ w3, const float* __restrict__ b3,
    float* __restrict__ K)
{
    __shared__ float a1[HU], wc1[HU], wo1[HU], b1s[HU], b2s[HU], w3s[HU];
    __shared__ float w2n[HU][HU];
    __shared__ float psum[4][64];
    __shared__ float b3s;

    const int tid = threadIdx.x;
    if (tid < HU) {
        float vx = v1[tid * 3 + 0];
        float vy = v1[tid * 3 + 1];
        float vz = v1[tid * 3 + 2];
        float inv = g1[tid] * rsqrtf(vx * vx + vy * vy + vz * vz);
        a1[tid]  = vx * inv;
        wc1[tid] = vy * inv;
        wo1[tid] = vz * inv;
        b1s[tid] = b1[tid];
        b2s[tid] = b2[tid];
        w3s[tid] = w3[tid];
        float s = 0.f;
        #pragma unroll
        for (int h = 0; h < HU; ++h) {
            float v = v2[tid * HU + h];
            s += v * v;
        }
        float inv2 = g2[tid] * rsqrtf(s);
        #pragma unroll
        for (int h = 0; h < HU; ++h)
            w2n[tid][h] = v2[tid * HU + h] * inv2;
    }
    if (tid == 0) b3s = b3[0];
    __syncthreads();

    const int p  = tid & 63;                  // point within block
    const int kq = tid >> 6;                  // wave id = k-quarter (0..3)
    const int g  = (blockIdx.x << 6) | p;     // global point id 0..16383
    const int d  = g & (LSEQ - 1);
    const int oc = g >> 8;                    // (o*8 + c)
    const float cf = (float)(oc & 7);
    const float of = (float)(oc >> 3);
    const float dt = -(float)d * (1.0f / (float)LSEQ);

    // layer 1 (redundant per wave, cheap with native sin)
    float h1[HU];
    #pragma unroll
    for (int h = 0; h < HU; ++h) {
        float z = fmaf(dt, a1[h], fmaf(cf, wc1[h], fmaf(of, wo1[h], b1s[h])));
        h1[h] = __sinf(z);
    }

    // layer 2: this wave's 8 k-rows; w2n[k][*] is wave-uniform (broadcast)
    float acc = 0.f;
    #pragma unroll
    for (int kk = 0; kk < 8; ++kk) {
        const int k = (kq << 3) | kk;
        float z = b2s[k];
        #pragma unroll
        for (int h = 0; h < HU; ++h)
            z = fmaf(h1[h], w2n[k][h], z);
        acc = fmaf(__sinf(z), w3s[k], acc);
    }
    psum[kq][p] = acc;
    __syncthreads();
    if (kq == 0)
        K[g] = psum[0][p] + psum[1][p] + psum[2][p] + psum[3][p] + b3s;
}

// ---------------------------------------------------------------------------
// Kernel 2: causal conv  out[i,o] = sum_c sum_{j<=i} K[o,c,i-j] * x[j,c]
// One WAVE per (i,o): lane = (jf<<3)|c ; lane sums j = jf, jf+8, ... <= i
// for its fixed c, then 6-step shfl_xor reduces all 64 lanes.
// Grid: 512 blocks x 256 threads = 2048 waves.
// ---------------------------------------------------------------------------
__global__ __launch_bounds__(256) void ck_conv(
    const float* __restrict__ x, const float* __restrict__ K,
    float* __restrict__ out)
{
    const int tid  = threadIdx.x;
    const int lane = tid & 63;
    const int wid  = (blockIdx.x << 2) | (tid >> 6);   // 0..2047
    const int i = wid >> 3;                            // 0..255
    const int o = wid & 7;
    const int c  = lane & 7;
    const int jf = lane >> 3;                          // 0..7

    const float* Kr = K + ((o * CIN + c) << 8) + i;    // Kr[-j] = K[o,c,i-j]
    float a = 0.f;
    for (int j = jf; j <= i; j += 8)
        a = fmaf(Kr[-j], x[j * CIN + c], a);

    // full-wave sum (over c and jf)
    a += __shfl_xor(a, 1);
    a += __shfl_xor(a, 2);
    a += __shfl_xor(a, 4);
    a += __shfl_xor(a, 8);
    a += __shfl_xor(a, 16);
    a += __shfl_xor(a, 32);
    if (lane == 0) out[i * COUT + o] = a;
}

extern "C" void kernel_launch(void* const* d_in, const int* in_sizes, int n_in,
                              void* d_out, int out_size, void* d_ws, size_t ws_size,
                              hipStream_t stream) {
    const float* x  = (const float*)d_in[0];
    // d_in[1] = t (unused: t = arange(L)/L so dt = -(i-j)/L in closed form)
    const float* v1 = (const float*)d_in[2];
    const float* g1 = (const float*)d_in[3];
    const float* b1 = (const float*)d_in[4];
    const float* v2 = (const float*)d_in[5];
    const float* g2 = (const float*)d_in[6];
    const float* b2 = (const float*)d_in[7];
    const float* w3 = (const float*)d_in[8];
    const float* b3 = (const float*)d_in[9];
    float* out = (float*)d_out;
    float* K   = (float*)d_ws;  // COUT*CIN*LSEQ floats = 64 KiB

    ck_gen<<<dim3(256), dim3(256), 0, stream>>>(
        v1, g1, b1, v2, g2, b2, w3, b3, K);
    ck_conv<<<dim3(512), dim3(256), 0, stream>>>(x, K, out);
}